// Round 11
// baseline (55.790 us; speedup 1.0000x reference)
//
#include <hip/hip_runtime.h>

// Problem constants (B,S,D,R) = (4,1024,1024,64)
#define SS 1024
#define DD 1024
#define RR 64
#define NB 4
#define NROWS (NB * SS)   // 4096

// ---- proj v3: 256-row x 64-col tile, KSPLIT=16, 8x8 per thread ------------
#define P_ROWS 256
#define P_KSPLIT 16
#define P_BK 64
#define ATS 260

#define T_F    ((size_t)NROWS * RR)            // 256K floats = 1 MB
#define PART_F ((size_t)P_KSPLIT * T_F)        // 4M floats = 16 MB
#define WS_NEED ((PART_F + T_F) * 4)           // 17 MB

// ---------------------------------------------------------------------------
// proj16 (identical to round 10)
// ---------------------------------------------------------------------------
__global__ __launch_bounds__(256) void proj16_kernel(const float* __restrict__ batch,
                                                     const float* __restrict__ proj,
                                                     float* __restrict__ part) {
    __shared__ __align__(16) float AT[P_BK][ATS];   // [k][row]
    __shared__ __align__(16) float Pt[P_BK][RR];    // [k][r]

    const int tid   = threadIdx.x;
    const int strip = blockIdx.x >> 4;
    const int slice = blockIdx.x & 15;
    const int row0  = strip * P_ROWS;
    const int kbase = slice * P_BK;

    {
        const int rbase = tid >> 4;
        const int k4    = tid & 15;
        float4 v[16];
#pragma unroll
        for (int p = 0; p < 16; ++p) {
            const int row = rbase + p * 16;
            v[p] = *reinterpret_cast<const float4*>(
                &batch[(size_t)(row0 + row) * DD + kbase + k4 * 4]);
        }
#pragma unroll
        for (int p = 0; p < 16; ++p) {
            const int row = rbase + p * 16;
            AT[k4 * 4 + 0][row] = v[p].x;
            AT[k4 * 4 + 1][row] = v[p].y;
            AT[k4 * 4 + 2][row] = v[p].z;
            AT[k4 * 4 + 3][row] = v[p].w;
        }
        const float4* psrc = reinterpret_cast<const float4*>(proj + (size_t)kbase * RR);
#pragma unroll
        for (int i = 0; i < 4; ++i)
            reinterpret_cast<float4*>(Pt)[i * 256 + tid] = psrc[i * 256 + tid];
    }
    __syncthreads();

    const int tx = tid & 7;
    const int ty = tid >> 3;

    float acc[8][8];
#pragma unroll
    for (int i = 0; i < 8; ++i)
#pragma unroll
        for (int j = 0; j < 8; ++j) acc[i][j] = 0.0f;

#pragma unroll 4
    for (int k = 0; k < P_BK; ++k) {
        const float4 a0 = *reinterpret_cast<const float4*>(&AT[k][ty * 8 + 0]);
        const float4 a1 = *reinterpret_cast<const float4*>(&AT[k][ty * 8 + 4]);
        const float4 p0 = *reinterpret_cast<const float4*>(&Pt[k][tx * 8 + 0]);
        const float4 p1 = *reinterpret_cast<const float4*>(&Pt[k][tx * 8 + 4]);
        const float a[8] = {a0.x, a0.y, a0.z, a0.w, a1.x, a1.y, a1.z, a1.w};
        const float p[8] = {p0.x, p0.y, p0.z, p0.w, p1.x, p1.y, p1.z, p1.w};
#pragma unroll
        for (int i = 0; i < 8; ++i)
#pragma unroll
            for (int j = 0; j < 8; ++j)
                acc[i][j] = fmaf(a[i], p[j], acc[i][j]);
    }

    float* slice_p = part + (size_t)slice * T_F;
#pragma unroll
    for (int i = 0; i < 8; ++i) {
        const size_t base = (size_t)(row0 + ty * 8 + i) * RR + tx * 8;
        float4 o0 = {acc[i][0], acc[i][1], acc[i][2], acc[i][3]};
        float4 o1 = {acc[i][4], acc[i][5], acc[i][6], acc[i][7]};
        *reinterpret_cast<float4*>(&slice_p[base + 0]) = o0;
        *reinterpret_cast<float4*>(&slice_p[base + 4]) = o1;
    }
}

__global__ __launch_bounds__(256) void reduce16_kernel(const float* __restrict__ part,
                                                       float* __restrict__ t) {
    const int idx = blockIdx.x * 256 + threadIdx.x;
    const float4* p4 = reinterpret_cast<const float4*>(part);
    float4 s = p4[idx];
#pragma unroll
    for (int sl = 1; sl < P_KSPLIT; ++sl) {
        const float4 v = p4[(size_t)sl * (T_F / 4) + idx];
        s.x += v.x; s.y += v.y; s.z += v.z; s.w += v.w;
    }
    reinterpret_cast<float4*>(t)[idx] = s;
}

// ---------------------------------------------------------------------------
// dist (identical to round 10)
// ---------------------------------------------------------------------------
#define TPAD 68

__global__ __launch_bounds__(256) void dist_kernel(const float* __restrict__ t,
                                                   float* __restrict__ out) {
    __shared__ __align__(16) float tiT[RR][TPAD];
    __shared__ __align__(16) float tjT[RR][TPAD];
    __shared__ float ni[64];
    __shared__ float nj[64];

    const int b  = blockIdx.z;
    const int i0 = blockIdx.y * 64;
    const int j0 = blockIdx.x * 64;
    const int tid = threadIdx.x;

    for (int idx = tid; idx < 2048; idx += 256) {
        const int tile = idx >> 10;
        const int e    = idx & 1023;
        const int row  = e >> 4;
        const int rseg = e & 15;
        const int src_row = b * SS + (tile ? j0 : i0) + row;
        const float4 v =
            *reinterpret_cast<const float4*>(&t[(size_t)src_row * RR + rseg * 4]);
        float (*dst)[TPAD] = tile ? tjT : tiT;
        dst[rseg * 4 + 0][row] = v.x;
        dst[rseg * 4 + 1][row] = v.y;
        dst[rseg * 4 + 2][row] = v.z;
        dst[rseg * 4 + 3][row] = v.w;
    }
    __syncthreads();

    if (tid < 128) {
        const int row = tid & 63;
        float (*src)[TPAD] = (tid >> 6) ? tjT : tiT;
        float s = 0.0f;
#pragma unroll
        for (int r = 0; r < RR; ++r) {
            const float v = src[r][row];
            s = fmaf(v, v, s);
        }
        if (tid >> 6) nj[row] = s; else ni[row] = s;
    }
    __syncthreads();

    const int tx = tid & 15;
    const int ty = tid >> 4;

    float acc[4][4];
#pragma unroll
    for (int i = 0; i < 4; ++i)
#pragma unroll
        for (int j = 0; j < 4; ++j) acc[i][j] = 0.0f;

#pragma unroll 4
    for (int r = 0; r < RR; ++r) {
        const float4 av = *reinterpret_cast<const float4*>(&tiT[r][ty * 4]);
        const float4 bv = *reinterpret_cast<const float4*>(&tjT[r][tx * 4]);
        const float a[4] = {av.x, av.y, av.z, av.w};
        const float c[4] = {bv.x, bv.y, bv.z, bv.w};
#pragma unroll
        for (int i = 0; i < 4; ++i)
#pragma unroll
            for (int j = 0; j < 4; ++j)
                acc[i][j] = fmaf(a[i], c[j], acc[i][j]);
    }

    const float nrow[4] = {ni[ty*4+0], ni[ty*4+1], ni[ty*4+2], ni[ty*4+3]};
    const float ncol[4] = {nj[tx*4+0], nj[tx*4+1], nj[tx*4+2], nj[tx*4+3]};
#pragma unroll
    for (int i = 0; i < 4; ++i) {
        float4 o;
        o.x = fmaf(-2.0f, acc[i][0], nrow[i] + ncol[0]);
        o.y = fmaf(-2.0f, acc[i][1], nrow[i] + ncol[1]);
        o.z = fmaf(-2.0f, acc[i][2], nrow[i] + ncol[2]);
        o.w = fmaf(-2.0f, acc[i][3], nrow[i] + ncol[3]);
        *reinterpret_cast<float4*>(
            &out[((size_t)(b * SS + i0 + ty * 4 + i)) * SS + j0 + tx * 4]) = o;
    }
}

// ---- fallback bits (tiny ws) ----------------------------------------------
__global__ __launch_bounds__(256) void zero_kernel(float* __restrict__ t) {
    const int idx = blockIdx.x * 256 + threadIdx.x;
    reinterpret_cast<float4*>(t)[idx] = {0.0f, 0.0f, 0.0f, 0.0f};
}

__global__ __launch_bounds__(256) void proj_atomic_kernel(const float* __restrict__ batch,
                                                          const float* __restrict__ proj,
                                                          float* __restrict__ t) {
    __shared__ __align__(16) float AT[64][68];
    __shared__ __align__(16) float Pt[64][RR];
    const int tid = threadIdx.x;
    const int row0 = blockIdx.x * 64;
    const int kbase = blockIdx.y * 128;
    const int tx = tid & 15, ty = tid >> 4;
    float acc[4][4] = {{0.0f}};
    for (int kt = 0; kt < 2; ++kt) {
        const int k0 = kbase + kt * 64;
        __syncthreads();
#pragma unroll
        for (int i = 0; i < 4; ++i) {
            const float4 a = *reinterpret_cast<const float4*>(
                &batch[(size_t)(row0 + i * 16 + ty) * DD + k0 + tx * 4]);
            AT[tx*4+0][i*16+ty] = a.x; AT[tx*4+1][i*16+ty] = a.y;
            AT[tx*4+2][i*16+ty] = a.z; AT[tx*4+3][i*16+ty] = a.w;
            reinterpret_cast<float4*>(Pt)[i * 256 + tid] =
                reinterpret_cast<const float4*>(proj + (size_t)k0 * RR)[i * 256 + tid];
        }
        __syncthreads();
#pragma unroll 8
        for (int k = 0; k < 64; ++k) {
            const float4 av = *reinterpret_cast<const float4*>(&AT[k][ty * 4]);
            const float4 pv = *reinterpret_cast<const float4*>(&Pt[k][tx * 4]);
            const float a[4] = {av.x, av.y, av.z, av.w};
            const float p[4] = {pv.x, pv.y, pv.z, pv.w};
#pragma unroll
            for (int i = 0; i < 4; ++i)
#pragma unroll
                for (int j = 0; j < 4; ++j)
                    acc[i][j] = fmaf(a[i], p[j], acc[i][j]);
        }
    }
#pragma unroll
    for (int i = 0; i < 4; ++i)
#pragma unroll
        for (int j = 0; j < 4; ++j)
            atomicAdd(&t[(size_t)(row0 + ty*4 + i) * RR + tx*4 + j], acc[i][j]);
}

// ---------------------------------------------------------------------------
extern "C" void kernel_launch(void* const* d_in, const int* in_sizes, int n_in,
                              void* d_out, int out_size, void* d_ws, size_t ws_size,
                              hipStream_t stream) {
    const float* batch = (const float*)d_in[0];  // (4,1024,1024) f32
    const float* proj  = (const float*)d_in[1];  // (1024,64) f32
    float* out = (float*)d_out;                  // (4,1024,1024) f32
    float* ws  = (float*)d_ws;

    dim3 gB(SS / 64, SS / 64, NB);

    if (ws_size >= WS_NEED) {
        float* part = ws;                        // 16 MB
        float* t    = ws + PART_F;               // 1 MB
        proj16_kernel<<<256, 256, 0, stream>>>(batch, proj, part);
        reduce16_kernel<<<256, 256, 0, stream>>>(part, t);
        dist_kernel<<<gB, 256, 0, stream>>>(t, out);
        // MEASUREMENT: idempotent duplicate of dist (same inputs -> same out).
        // Total-time delta vs round 10 (41.76us) = dist duration + 1 node
        // overhead. Discriminates: ~51 => proj+reduce slow; ~60 => per-node
        // overhead ~9us; ~72 => dist itself ~30us.
        dist_kernel<<<gB, 256, 0, stream>>>(t, out);
    } else {
        float* t = ws;
        zero_kernel<<<T_F / (256 * 4), 256, 0, stream>>>(t);
        dim3 gA(NROWS / 64, 8, 1);
        proj_atomic_kernel<<<gA, 256, 0, stream>>>(batch, proj, t);
        dist_kernel<<<gB, 256, 0, stream>>>(t, out);
    }
}